// Round 5
// baseline (600.328 us; speedup 1.0000x reference)
//
#include <hip/hip_runtime.h>
#include <hip/hip_bf16.h>

// Attention_aux: fused aux-attention scorer + context + output projection.
//   1. convw1:   W1[:, :3072] -> bf16 (ws)
//   2. hbias:    hb[b,d] = hs[b,:]·W1[d,3072:] + b1[d]  (fp32)
//   3. gemm_score: bf16 MFMA  pre = enc·W1a^T ; epilogue p = sum tanh(pre+hb)*w2
//      m201-style 8-phase schedule: 256x256 tile, BK=64, 8 waves (2Mx4N),
//      4 phases per K-tile (16 MFMA each), dbuf 128KB LDS, counted vmcnt,
//      raw s_barrier + lgkmcnt(0) + sched_barrier(0) per phase, setprio (T5),
//      8-slot XOR swizzle (T2). A = fp32 reg-staged via cvt_pk (T14 split);
//      B via global_load_lds with pre-swizzled source (rule 21).
//   4. softmax over S -> alpha
//   5. ctxpart/ctxreduce: context = alpha^T · enc  (fp32, deterministic)
//   6. final:    out = context·W3^T + b3

typedef float          fx4 __attribute__((ext_vector_type(4)));
typedef short          sv8 __attribute__((ext_vector_type(8)));
typedef unsigned short uv4 __attribute__((ext_vector_type(4)));
typedef unsigned int   ui4 __attribute__((ext_vector_type(4)));

__device__ __forceinline__ unsigned short f2bf(float x) {
  unsigned u = __float_as_uint(x);
  return (unsigned short)((u + 0x7FFFu + ((u >> 16) & 1u)) >> 16);
}

// packed RNE f32x2 -> bf16x2 via HW instruction
__device__ __forceinline__ unsigned cvtpk(float lo, float hi) {
  unsigned r;
  asm("v_cvt_pk_bf16_f32 %0, %1, %2" : "=v"(r) : "v"(lo), "v"(hi));
  return r;
}
__device__ __forceinline__ ui4 pack8(fx4 a, fx4 b) {
  ui4 v;
  v[0] = cvtpk(a[0], a[1]); v[1] = cvtpk(a[2], a[3]);
  v[2] = cvtpk(b[0], b[1]); v[3] = cvtpk(b[2], b[3]);
  return v;
}

// ---------------- kernel 1: convert W1[:, :3072] to bf16 ----------------
__global__ void convw1_kernel(const float* __restrict__ W1, unsigned short* __restrict__ W1a) {
  int id = blockIdx.x * 256 + threadIdx.x;      // float4 id, 1024*768 total
  int d = id / 768, fi = id - d * 768;
  fx4 v = ((const fx4*)W1)[d * 1024 + fi];
  uv4 r; r[0] = f2bf(v[0]); r[1] = f2bf(v[1]); r[2] = f2bf(v[2]); r[3] = f2bf(v[3]);
  ((uv4*)W1a)[d * 768 + fi] = r;
}

// ---------------- kernel 2: hidden-state bias  hb[b,d] ----------------
__global__ void hbias_kernel(const float* __restrict__ hs, const float* __restrict__ W1,
                             const float* __restrict__ b1, float* __restrict__ hb) {
  int idx = (blockIdx.x << 2) + (threadIdx.x >> 6);   // 0..32767 = b*1024+d
  int lane = threadIdx.x & 63;
  int b = idx >> 10, d = idx & 1023;
  const fx4* hv = (const fx4*)hs;
  const fx4* wv = (const fx4*)W1;
  float s = 0.f;
#pragma unroll
  for (int i = 0; i < 4; ++i) {
    int k4 = lane + (i << 6);
    fx4 h = hv[(b << 8) + k4];
    fx4 w = wv[d * 1024 + 768 + k4];
    s += h[0] * w[0] + h[1] * w[1] + h[2] * w[2] + h[3] * w[3];
  }
#pragma unroll
  for (int off = 32; off; off >>= 1) s += __shfl_xor(s, off);
  if (lane == 0) hb[idx] = s + b1[d];
}

// ---------------- kernel 3: big GEMM + tanh·w2 epilogue ----------------
// M=32768, N=1024, K=3072. Block 256x256, BK=64, 48 K-tiles, 8 waves
// (2M x 4N), wave tile 128x64 (acc 8x4). 4 phases/K-tile, each: {ds_read
// quadrant frags, issue stage ops, barrier, lgkm0, sched_barrier, 16 MFMA,
// barrier}. A(kt+1) fp32 loads issued P1/P2, cvt+ds_write P3/P4. B halves
// issued P4(kt-1)/P1(kt) via global_load_lds. vmcnt(2) once per tile.
__global__ __launch_bounds__(512, 2)
void gemm_score(const float* __restrict__ enc,
                const unsigned short* __restrict__ W1a,
                const float* __restrict__ hb,
                const float* __restrict__ w2,
                float* __restrict__ pe) {
  __shared__ __align__(16) unsigned short As[2][16384];   // [256 rows][64 k]
  __shared__ __align__(16) unsigned short Bs[2][16384];   // [256 cols][64 k]

  const int t = threadIdx.x;
  const int lane = t & 63, wid = t >> 6;
  const int wm = wid >> 2, wn = wid & 3;          // 2 x 4 wave grid

  // XCD-bijective swizzle: 512 blocks, XCD x owns lg [x*64, x*64+64)
  const int bid = blockIdx.x;
  const int lg = ((bid & 7) << 6) | (bid >> 3);
  const int mt = lg >> 2, nt = lg & 3;
  const int row0 = mt << 8;            // 256-row M tile
  const int col0 = nt << 8;            // 256-col N tile

  const fx4* encv = (const fx4*)enc;   // enc row = 768 fx4

  // ---- A staging: thread t -> row t>>1, k-half (t&1)*32 floats ----
  const int ar = t >> 1, akh = t & 1;
  const int agb = (row0 + ar) * 768 + akh * 8;    // fx4 index; + kt*16
  const int awb = ar * 64;                        // LDS elem base of row
  const int aws0 = (((akh << 2) + 0) ^ (ar & 7)) << 3;  // swizzled slots
  const int aws1 = (((akh << 2) + 1) ^ (ar & 7)) << 3;
  const int aws2 = (((akh << 2) + 2) ^ (ar & 7)) << 3;
  const int aws3 = (((akh << 2) + 3) ^ (ar & 7)) << 3;

  // ---- B staging: 4 gload_lds/wave/tile; i = half*2 + chunk ----
  // dest linear (wave base + lane*16); source k pre-swizzled (rule 21)
  const unsigned short* bsrcp[4];
  int bdstp[4];
#pragma unroll
  for (int i = 0; i < 4; ++i) {
    int colbase = (i >> 1) * 128 + wid * 16 + (i & 1) * 8;
    int col_l = colbase + (lane >> 3);
    bsrcp[i] = W1a + (col0 + col_l) * 3072 + (((lane & 7) ^ ((lane >> 3) & 7)) << 3);
    bdstp[i] = colbase << 6;
  }

  // ---- fragment read offsets (slot = (kh*4+q) ^ (row&7)) ----
  const int r15 = lane & 15, qv = lane >> 4, r7 = r15 & 7;
  const int offA0 = (wm * 128 + r15) * 64 + ((qv ^ r7) << 3);
  const int offA1 = (wm * 128 + r15) * 64 + (((qv + 4) ^ r7) << 3);
  const int offB0 = (wn * 64 + r15) * 64 + ((qv ^ r7) << 3);
  const int offB1 = (wn * 64 + r15) * 64 + (((qv + 4) ^ r7) << 3);

  fx4 acc[8][4] = {};
  fx4 pa0[4], pa1[4];
  sv8 af[4], bfv[4];

#define A_LOAD0(kt) { _Pragma("unroll") for (int j = 0; j < 4; ++j) pa0[j] = encv[agb + (kt) * 16 + j]; }
#define A_LOAD1(kt) { _Pragma("unroll") for (int j = 0; j < 4; ++j) pa1[j] = encv[agb + (kt) * 16 + 4 + j]; }
#define A_WRITE0(buf) { *(ui4*)&As[buf][awb + aws0] = pack8(pa0[0], pa0[1]); \
                        *(ui4*)&As[buf][awb + aws1] = pack8(pa0[2], pa0[3]); }
#define A_WRITE1(buf) { *(ui4*)&As[buf][awb + aws2] = pack8(pa1[0], pa1[1]); \
                        *(ui4*)&As[buf][awb + aws3] = pack8(pa1[2], pa1[3]); }
#define B_ISSUE(buf, h, kt)                                           \
  { _Pragma("unroll")                                                 \
    for (int i = (h) * 2; i < (h) * 2 + 2; ++i)                       \
      __builtin_amdgcn_global_load_lds(                               \
          (const __attribute__((address_space(1))) void*)(bsrcp[i] + (kt) * 64), \
          (__attribute__((address_space(3))) void*)&Bs[buf][bdstp[i]], 16, 0, 0); }
#define LDA_FRAGS(bp, MH, OFFA)                                       \
  { _Pragma("unroll")                                                 \
    for (int mi = 0; mi < 4; ++mi)                                    \
      af[mi] = *(const sv8*)&As[bp][(OFFA) + (((MH) * 64 + mi * 16) << 6)]; }
#define LDB_FRAGS(bp, OFFB)                                           \
  { _Pragma("unroll")                                                 \
    for (int ni = 0; ni < 4; ++ni)                                    \
      bfv[ni] = *(const sv8*)&Bs[bp][(OFFB) + (ni << 10)]; }
#define BAR_LGKM_SCHED                                                \
  __builtin_amdgcn_s_barrier();                                       \
  asm volatile("s_waitcnt lgkmcnt(0)" ::: "memory");                  \
  __builtin_amdgcn_sched_barrier(0);
#define MFMA_Q(MB)                                                    \
  __builtin_amdgcn_s_setprio(1);                                      \
  { _Pragma("unroll")                                                 \
    for (int mi = 0; mi < 4; ++mi)                                    \
      _Pragma("unroll")                                               \
      for (int ni = 0; ni < 4; ++ni)                                  \
        acc[(MB) + mi][ni] = __builtin_amdgcn_mfma_f32_16x16x32_bf16(af[mi], bfv[ni], acc[(MB) + mi][ni], 0, 0, 0); } \
  __builtin_amdgcn_s_setprio(0);

#define TILE(kt, bp, bn)                                              \
  { /* P1: quadrant (mh0, kh0) */                                     \
    LDA_FRAGS(bp, 0, offA0)                                           \
    LDB_FRAGS(bp, offB0)                                              \
    if ((kt) < 47) { A_LOAD0((kt) + 1) B_ISSUE(bn, 1, (kt) + 1) }     \
    BAR_LGKM_SCHED                                                    \
    MFMA_Q(0)                                                         \
    __builtin_amdgcn_s_barrier();                                     \
    /* P2: (mh1, kh0) */                                              \
    LDA_FRAGS(bp, 1, offA0)                                           \
    if ((kt) < 47) { A_LOAD1((kt) + 1) }                              \
    BAR_LGKM_SCHED                                                    \
    MFMA_Q(4)                                                         \
    __builtin_amdgcn_s_barrier();                                     \
    /* P3: (mh0, kh1) */                                              \
    LDA_FRAGS(bp, 0, offA1)                                           \
    LDB_FRAGS(bp, offB1)                                              \
    if ((kt) < 47) { A_WRITE0(bn) }                                   \
    BAR_LGKM_SCHED                                                    \
    MFMA_Q(0)                                                         \
    __builtin_amdgcn_s_barrier();                                     \
    /* P4: (mh1, kh1) */                                              \
    LDA_FRAGS(bp, 1, offA1)                                           \
    if ((kt) < 46) { B_ISSUE(bp, 0, (kt) + 2) }                       \
    if ((kt) < 47) { A_WRITE1(bn) }                                   \
    BAR_LGKM_SCHED                                                    \
    MFMA_Q(4)                                                         \
    if ((kt) < 46) { asm volatile("s_waitcnt vmcnt(2)" ::: "memory"); } \
    else if ((kt) < 47) { asm volatile("s_waitcnt vmcnt(0)" ::: "memory"); } \
    __builtin_amdgcn_s_barrier(); }

  // ---- prologue: stage tile 0 into buf 0, B h0(1) into buf 1 ----
  B_ISSUE(0, 0, 0)
  B_ISSUE(0, 1, 0)
  A_LOAD0(0)
  A_LOAD1(0)
  A_WRITE0(0)                // compiler waits pa0 loads (drains B(0) too)
  A_WRITE1(0)
  B_ISSUE(1, 0, 1)
  asm volatile("s_waitcnt vmcnt(2)" ::: "memory");   // B(0) certainly landed
  asm volatile("s_waitcnt lgkmcnt(0)" ::: "memory");
  __builtin_amdgcn_s_barrier();

  // ---- main loop: 48 K-tiles ----
  for (int kt = 0; kt < 48; kt += 2) {
    TILE(kt, 0, 1)
    TILE(kt + 1, 1, 0)
  }

  // ---- epilogue: p[row] += sum_{cols in tile} tanh(acc + hb) * w2 ----
  // C layout: col = lane&15 (N), row = (lane>>4)*4 + j (M)
  const int b = row0 >> 10;
  float w2v[4], hbv[4];
#pragma unroll
  for (int ni = 0; ni < 4; ++ni) {
    int c = col0 + wn * 64 + ni * 16 + r15;
    w2v[ni] = w2[c];
    hbv[ni] = hb[(b << 10) + c];
  }
#pragma unroll
  for (int mi = 0; mi < 8; ++mi) {
#pragma unroll
    for (int j = 0; j < 4; ++j) {
      float pz = 0.f;
#pragma unroll
      for (int ni = 0; ni < 4; ++ni)
        pz += tanhf(acc[mi][ni][j] + hbv[ni]) * w2v[ni];
      pz += __shfl_xor(pz, 1); pz += __shfl_xor(pz, 2);
      pz += __shfl_xor(pz, 4); pz += __shfl_xor(pz, 8);
      if (r15 == 0) {
        int row = row0 + wm * 128 + mi * 16 + (qv << 2) + j;
        pe[(row << 4) + (nt << 2) + wn] = pz;   // 16 deterministic slots/row
      }
    }
  }
#undef A_LOAD0
#undef A_LOAD1
#undef A_WRITE0
#undef A_WRITE1
#undef B_ISSUE
#undef LDA_FRAGS
#undef LDB_FRAGS
#undef BAR_LGKM_SCHED
#undef MFMA_Q
#undef TILE
}

// ---------------- kernel 4: softmax over S per batch ----------------
__global__ void softmax_kernel(const float* __restrict__ pe, float* __restrict__ alpha) {
  int b = blockIdx.x, t = threadIdx.x;
  int lane = t & 63, wid = t >> 6;
  float ev[4];
#pragma unroll
  for (int r = 0; r < 4; ++r) {
    int s = t + r * 256;
    const float* p = pe + ((b << 10) + s) * 16;
    float sum = 0.f;
#pragma unroll
    for (int i = 0; i < 16; ++i) sum += p[i];
    ev[r] = sum;
  }
  float m = fmaxf(fmaxf(ev[0], ev[1]), fmaxf(ev[2], ev[3]));
#pragma unroll
  for (int off = 32; off; off >>= 1) m = fmaxf(m, __shfl_xor(m, off));
  __shared__ float red[8];
  if (lane == 0) red[wid] = m;
  __syncthreads();
  m = fmaxf(fmaxf(red[0], red[1]), fmaxf(red[2], red[3]));
  float p4[4], ls = 0.f;
#pragma unroll
  for (int r = 0; r < 4; ++r) { p4[r] = expf(ev[r] - m); ls += p4[r]; }
#pragma unroll
  for (int off = 32; off; off >>= 1) ls += __shfl_xor(ls, off);
  if (lane == 0) red[4 + wid] = ls;
  __syncthreads();
  float inv = 1.0f / (red[4] + red[5] + red[6] + red[7]);
#pragma unroll
  for (int r = 0; r < 4; ++r) alpha[(b << 10) + t + r * 256] = p4[r] * inv;
}

// ---------------- kernel 5: context partials over s-chunks ----------------
__global__ void ctxpart_kernel(const float* __restrict__ enc, const float* __restrict__ alpha,
                               float* __restrict__ part) {
  int bid = blockIdx.x, b = bid >> 4, sc = bid & 15;
  int t = threadIdx.x;
  __shared__ float sal[64];
  if (t < 64) sal[t] = alpha[(b << 10) + (sc << 6) + t];
  __syncthreads();
  const fx4* ev = (const fx4*)enc;
  fx4 a0 = {}, a1 = {}, a2 = {};
  int base = ((b << 10) + (sc << 6)) * 768;
  for (int si = 0; si < 64; ++si) {
    float a = sal[si];
    const fx4* rp = ev + base + si * 768;
    a0 += a * rp[t];
    a1 += a * rp[256 + t];
    a2 += a * rp[512 + t];
  }
  fx4* pp = (fx4*)part;
  int pb = ((b << 4) + sc) * 768;
  pp[pb + t] = a0; pp[pb + 256 + t] = a1; pp[pb + 512 + t] = a2;
}

__global__ void ctxreduce_kernel(const float* __restrict__ part, float* __restrict__ ctx) {
  int j = blockIdx.x * 256 + threadIdx.x;     // 0..24575 fx4
  int b = j / 768, fi = j - b * 768;
  const fx4* pp = (const fx4*)part;
  fx4 s = {};
#pragma unroll
  for (int i = 0; i < 16; ++i) s += pp[((b << 4) + i) * 768 + fi];
  ((fx4*)ctx)[b * 768 + fi] = s;
}

// ---------------- kernel 6: out = ctx·W3^T + b3 ----------------
__global__ void final_kernel(const float* __restrict__ ctx, const float* __restrict__ W3,
                             const float* __restrict__ b3, float* __restrict__ out) {
  int idx = (blockIdx.x << 2) + (threadIdx.x >> 6);   // b*1024 + d
  int lane = threadIdx.x & 63;
  int b = idx >> 10, d = idx & 1023;
  const fx4* cv = (const fx4*)ctx;
  const fx4* wv = (const fx4*)W3;
  float s = 0.f;
#pragma unroll
  for (int i = 0; i < 12; ++i) {
    int f4 = lane + (i << 6);
    fx4 c = cv[b * 768 + f4];
    fx4 w = wv[d * 768 + f4];
    s += c[0] * w[0] + c[1] * w[1] + c[2] * w[2] + c[3] * w[3];
  }
#pragma unroll
  for (int off = 32; off; off >>= 1) s += __shfl_xor(s, off);
  if (lane == 0) out[idx] = s + b3[d];
}

extern "C" void kernel_launch(void* const* d_in, const int* in_sizes, int n_in,
                              void* d_out, int out_size, void* d_ws, size_t ws_size,
                              hipStream_t stream) {
  const float* hs  = (const float*)d_in[0];   // (32, 1024)
  const float* enc = (const float*)d_in[1];   // (32, 1024, 3072)
  const float* W1  = (const float*)d_in[2];   // (1024, 4096)
  const float* b1  = (const float*)d_in[3];   // (1024)
  const float* w2  = (const float*)d_in[4];   // (1, 1024)
  const float* W3  = (const float*)d_in[5];   // (1024, 3072)
  const float* b3  = (const float*)d_in[6];   // (1024)
  float* out = (float*)d_out;

  char* ws = (char*)d_ws;                     // ~15.3 MB used, write-before-read
  unsigned short* W1a = (unsigned short*)(ws);          // 6,291,456 B
  float* pe    = (float*)(ws + 6291456);                // 2,097,152 B
  float* alpha = (float*)(ws + 8388608);                // 131,072 B
  float* hb    = (float*)(ws + 8519680);                // 131,072 B
  float* ctx   = (float*)(ws + 8650752);                // 393,216 B
  float* part  = (float*)(ws + 9043968);                // 6,291,456 B

  convw1_kernel<<<3072, 256, 0, stream>>>(W1, W1a);
  hbias_kernel<<<8192, 256, 0, stream>>>(hs, W1, b1, hb);
  gemm_score<<<512, 512, 0, stream>>>(enc, W1a, hb, w2, pe);
  softmax_kernel<<<32, 256, 0, stream>>>(pe, alpha);
  ctxpart_kernel<<<512, 256, 0, stream>>>(enc, alpha, part);
  ctxreduce_kernel<<<96, 256, 0, stream>>>(part, ctx);
  final_kernel<<<8192, 256, 0, stream>>>(ctx, W3, b3, out);
}

// Round 6
// 540.792 us; speedup vs baseline: 1.1101x; 1.1101x over previous
//
#include <hip/hip_runtime.h>
#include <hip/hip_bf16.h>

// Attention_aux: fused aux-attention scorer + context + output projection.
//   1. convw1:   W1[:, :3072] -> bf16 (ws)
//   2. hbias:    hb[b,d] = hs[b,:]·W1[d,3072:] + b1[d]  (fp32)
//   3. gemm_score: bf16 MFMA  pre = enc·W1a^T ; epilogue p = sum tanh(pre+hb)*w2
//      m201-faithful 8-phase: 256x256, BK=64, 8 waves, 4 phases/K-tile
//      (16 MFMA each), {ds_read frags, stage issue, bar, lgkm0, setprio,
//      MFMA, setprio, bar}. NO sched_barrier (m141). Counted vmcnt (T4).
//      8-slot XOR swizzle (T2), conflict-free (verified R5: 0 conflicts).
//      A = fp32 reg-staged via cvt_pk; B via global_load_lds (rule 21).
//   4. softmax over S -> alpha
//   5. ctxpart/ctxreduce: context = alpha^T · enc  (fp32, deterministic)
//   6. final:    out = context·W3^T + b3

typedef float          fx4 __attribute__((ext_vector_type(4)));
typedef short          sv8 __attribute__((ext_vector_type(8)));
typedef unsigned short uv4 __attribute__((ext_vector_type(4)));
typedef unsigned int   ui4 __attribute__((ext_vector_type(4)));

__device__ __forceinline__ unsigned short f2bf(float x) {
  unsigned u = __float_as_uint(x);
  return (unsigned short)((u + 0x7FFFu + ((u >> 16) & 1u)) >> 16);
}

// packed RNE f32x2 -> bf16x2 via HW instruction
__device__ __forceinline__ unsigned cvtpk(float lo, float hi) {
  unsigned r;
  asm("v_cvt_pk_bf16_f32 %0, %1, %2" : "=v"(r) : "v"(lo), "v"(hi));
  return r;
}
__device__ __forceinline__ ui4 pack8(fx4 a, fx4 b) {
  ui4 v;
  v[0] = cvtpk(a[0], a[1]); v[1] = cvtpk(a[2], a[3]);
  v[2] = cvtpk(b[0], b[1]); v[3] = cvtpk(b[2], b[3]);
  return v;
}

// ---------------- kernel 1: convert W1[:, :3072] to bf16 ----------------
__global__ void convw1_kernel(const float* __restrict__ W1, unsigned short* __restrict__ W1a) {
  int id = blockIdx.x * 256 + threadIdx.x;      // float4 id, 1024*768 total
  int d = id / 768, fi = id - d * 768;
  fx4 v = ((const fx4*)W1)[d * 1024 + fi];
  uv4 r; r[0] = f2bf(v[0]); r[1] = f2bf(v[1]); r[2] = f2bf(v[2]); r[3] = f2bf(v[3]);
  ((uv4*)W1a)[d * 768 + fi] = r;
}

// ---------------- kernel 2: hidden-state bias  hb[b,d] ----------------
__global__ void hbias_kernel(const float* __restrict__ hs, const float* __restrict__ W1,
                             const float* __restrict__ b1, float* __restrict__ hb) {
  int idx = (blockIdx.x << 2) + (threadIdx.x >> 6);   // 0..32767 = b*1024+d
  int lane = threadIdx.x & 63;
  int b = idx >> 10, d = idx & 1023;
  const fx4* hv = (const fx4*)hs;
  const fx4* wv = (const fx4*)W1;
  float s = 0.f;
#pragma unroll
  for (int i = 0; i < 4; ++i) {
    int k4 = lane + (i << 6);
    fx4 h = hv[(b << 8) + k4];
    fx4 w = wv[d * 1024 + 768 + k4];
    s += h[0] * w[0] + h[1] * w[1] + h[2] * w[2] + h[3] * w[3];
  }
#pragma unroll
  for (int off = 32; off; off >>= 1) s += __shfl_xor(s, off);
  if (lane == 0) hb[idx] = s + b1[d];
}

// ---------------- kernel 3: big GEMM + tanh·w2 epilogue ----------------
// M=32768, N=1024, K=3072. Block 256x256, BK=64, 48 K-tiles, 8 waves
// (2M x 4N), wave tile 128x64 (acc 8x4). 4 phases/K-tile. Staging of tile
// kt+1 spread over kt's phases: P1{pa0 loads, B h1}, P2{pa1 loads},
// P3{A_WRITE0}, P4{B(kt+2) h0, A_WRITE1}. A_WRITE's implicit pa-wait
// certifies all older B loads landed (FIFO). vmcnt(2) once per tile.
__global__ __launch_bounds__(512, 2)
void gemm_score(const float* __restrict__ enc,
                const unsigned short* __restrict__ W1a,
                const float* __restrict__ hb,
                const float* __restrict__ w2,
                float* __restrict__ pe) {
  __shared__ __align__(16) unsigned short As[2][16384];   // [256 rows][64 k]
  __shared__ __align__(16) unsigned short Bs[2][16384];   // [256 cols][64 k]

  const int t = threadIdx.x;
  const int lane = t & 63, wid = t >> 6;
  const int wm = wid >> 2, wn = wid & 3;          // 2 x 4 wave grid

  // XCD-bijective swizzle: 512 blocks, XCD x owns lg [x*64, x*64+64)
  const int bid = blockIdx.x;
  const int lg = ((bid & 7) << 6) | (bid >> 3);
  const int mt = lg >> 2, nt = lg & 3;
  const int row0 = mt << 8;            // 256-row M tile
  const int col0 = nt << 8;            // 256-col N tile

  const fx4* encv = (const fx4*)enc;   // enc row = 768 fx4

  // ---- A staging: thread t -> row t>>1, k-half (t&1)*32 floats ----
  const int ar = t >> 1, akh = t & 1;
  const int agb = (row0 + ar) * 768 + akh * 8;    // fx4 index; + kt*16
  const int awb = ar * 64;                        // LDS elem base of row
  const int aws0 = (((akh << 2) + 0) ^ (ar & 7)) << 3;  // swizzled slots
  const int aws1 = (((akh << 2) + 1) ^ (ar & 7)) << 3;
  const int aws2 = (((akh << 2) + 2) ^ (ar & 7)) << 3;
  const int aws3 = (((akh << 2) + 3) ^ (ar & 7)) << 3;

  // ---- B staging: 4 gload_lds/wave/tile; chunk i = half*2 + sub ----
  // uniform bases (SGPR-friendly) + one shared per-lane elem offset
  const int blane = (lane >> 3) * 3072 + (((lane & 7) ^ ((lane >> 3) & 7)) << 3);
  const unsigned short* bbase0 = W1a + (col0 + wid * 16) * 3072;          // h0 sub0
  const unsigned short* bbase1 = W1a + (col0 + wid * 16 + 8) * 3072;      // h0 sub1
  const unsigned short* bbase2 = W1a + (col0 + 128 + wid * 16) * 3072;    // h1 sub0
  const unsigned short* bbase3 = W1a + (col0 + 128 + wid * 16 + 8) * 3072;// h1 sub1
  const int bdst0 = (wid * 16) << 6;
  const int bdst1 = (wid * 16 + 8) << 6;
  const int bdst2 = (128 + wid * 16) << 6;
  const int bdst3 = (128 + wid * 16 + 8) << 6;

  // ---- fragment read offsets (slot = (kh*4+q) ^ (row&7)) ----
  const int r15 = lane & 15, qv = lane >> 4, r7 = r15 & 7;
  const int offA0 = (wm * 128 + r15) * 64 + ((qv ^ r7) << 3);
  const int offA1 = (wm * 128 + r15) * 64 + (((qv + 4) ^ r7) << 3);
  const int offB0 = (wn * 64 + r15) * 64 + ((qv ^ r7) << 3);
  const int offB1 = (wn * 64 + r15) * 64 + (((qv + 4) ^ r7) << 3);

  fx4 acc[8][4] = {};
  fx4 pa0[4], pa1[4];
  sv8 af[4], bfv[4];

#define A_LOAD0(kt) { _Pragma("unroll") for (int j = 0; j < 4; ++j) pa0[j] = encv[agb + (kt) * 16 + j]; }
#define A_LOAD1(kt) { _Pragma("unroll") for (int j = 0; j < 4; ++j) pa1[j] = encv[agb + (kt) * 16 + 4 + j]; }
#define A_WRITE0(buf) { *(ui4*)&As[buf][awb + aws0] = pack8(pa0[0], pa0[1]); \
                        *(ui4*)&As[buf][awb + aws1] = pack8(pa0[2], pa0[3]); }
#define A_WRITE1(buf) { *(ui4*)&As[buf][awb + aws2] = pack8(pa1[0], pa1[1]); \
                        *(ui4*)&As[buf][awb + aws3] = pack8(pa1[2], pa1[3]); }
#define B_ISSUE_H0(buf, kt)                                           \
  { __builtin_amdgcn_global_load_lds(                                 \
        (const __attribute__((address_space(1))) void*)(bbase0 + blane + (kt) * 64), \
        (__attribute__((address_space(3))) void*)&Bs[buf][bdst0], 16, 0, 0); \
    __builtin_amdgcn_global_load_lds(                                 \
        (const __attribute__((address_space(1))) void*)(bbase1 + blane + (kt) * 64), \
        (__attribute__((address_space(3))) void*)&Bs[buf][bdst1], 16, 0, 0); }
#define B_ISSUE_H1(buf, kt)                                           \
  { __builtin_amdgcn_global_load_lds(                                 \
        (const __attribute__((address_space(1))) void*)(bbase2 + blane + (kt) * 64), \
        (__attribute__((address_space(3))) void*)&Bs[buf][bdst2], 16, 0, 0); \
    __builtin_amdgcn_global_load_lds(                                 \
        (const __attribute__((address_space(1))) void*)(bbase3 + blane + (kt) * 64), \
        (__attribute__((address_space(3))) void*)&Bs[buf][bdst3], 16, 0, 0); }
#define LDA_FRAGS(bp, MH, OFFA)                                       \
  { _Pragma("unroll")                                                 \
    for (int mi = 0; mi < 4; ++mi)                                    \
      af[mi] = *(const sv8*)&As[bp][(OFFA) + (((MH) * 64 + mi * 16) << 6)]; }
#define LDB_FRAGS(bp, OFFB)                                           \
  { _Pragma("unroll")                                                 \
    for (int ni = 0; ni < 4; ++ni)                                    \
      bfv[ni] = *(const sv8*)&Bs[bp][(OFFB) + (ni << 10)]; }
#define PHASE_SYNC                                                    \
  __builtin_amdgcn_s_barrier();                                       \
  asm volatile("s_waitcnt lgkmcnt(0)" ::: "memory");
#define MFMA_Q(MB)                                                    \
  __builtin_amdgcn_s_setprio(1);                                      \
  { _Pragma("unroll")                                                 \
    for (int mi = 0; mi < 4; ++mi)                                    \
      _Pragma("unroll")                                               \
      for (int ni = 0; ni < 4; ++ni)                                  \
        acc[(MB) + mi][ni] = __builtin_amdgcn_mfma_f32_16x16x32_bf16(af[mi], bfv[ni], acc[(MB) + mi][ni], 0, 0, 0); } \
  __builtin_amdgcn_s_setprio(0);

#define TILE(kt, bp, bn)                                              \
  { /* P1: quadrant (mh0, kh0) */                                     \
    LDA_FRAGS(bp, 0, offA0)                                           \
    LDB_FRAGS(bp, offB0)                                              \
    if ((kt) < 47) { A_LOAD0((kt) + 1) B_ISSUE_H1(bn, (kt) + 1) }     \
    PHASE_SYNC                                                        \
    MFMA_Q(0)                                                         \
    __builtin_amdgcn_s_barrier();                                     \
    /* P2: (mh1, kh0), reuse bfv */                                   \
    LDA_FRAGS(bp, 1, offA0)                                           \
    if ((kt) < 47) { A_LOAD1((kt) + 1) }                              \
    PHASE_SYNC                                                        \
    MFMA_Q(4)                                                         \
    __builtin_amdgcn_s_barrier();                                     \
    /* P3: (mh0, kh1) */                                              \
    LDA_FRAGS(bp, 0, offA1)                                           \
    LDB_FRAGS(bp, offB1)                                              \
    if ((kt) < 47) { A_WRITE0(bn) }                                   \
    PHASE_SYNC                                                        \
    MFMA_Q(0)                                                         \
    __builtin_amdgcn_s_barrier();                                     \
    /* P4: (mh1, kh1) */                                              \
    LDA_FRAGS(bp, 1, offA1)                                           \
    if ((kt) < 46) { B_ISSUE_H0(bp, (kt) + 2) }                       \
    if ((kt) < 47) { A_WRITE1(bn) }                                   \
    PHASE_SYNC                                                        \
    MFMA_Q(4)                                                         \
    if ((kt) < 46) { asm volatile("s_waitcnt vmcnt(2)" ::: "memory"); } \
    else if ((kt) < 47) { asm volatile("s_waitcnt vmcnt(0)" ::: "memory"); } \
    __builtin_amdgcn_s_barrier(); }

  // ---- prologue: stage tile 0 into buf 0, B h0(1) into buf 1 ----
  B_ISSUE_H0(0, 0)
  B_ISSUE_H1(0, 0)
  A_LOAD0(0)
  A_LOAD1(0)
  A_WRITE0(0)                // compiler waits pa0 (drains B(0) too, older)
  A_WRITE1(0)
  B_ISSUE_H0(1, 1)
  asm volatile("s_waitcnt vmcnt(2)" ::: "memory");   // B(0) certainly landed
  asm volatile("s_waitcnt lgkmcnt(0)" ::: "memory");
  __builtin_amdgcn_s_barrier();

  // ---- main loop: 48 K-tiles ----
  for (int kt = 0; kt < 48; kt += 2) {
    TILE(kt, 0, 1)
    TILE(kt + 1, 1, 0)
  }

  // ---- epilogue: p[row] += sum_{cols in tile} tanh(acc + hb) * w2 ----
  // C layout: col = lane&15 (N), row = (lane>>4)*4 + j (M)
  const int b = row0 >> 10;
  float w2v[4], hbv[4];
#pragma unroll
  for (int ni = 0; ni < 4; ++ni) {
    int c = col0 + wn * 64 + ni * 16 + r15;
    w2v[ni] = w2[c];
    hbv[ni] = hb[(b << 10) + c];
  }
#pragma unroll
  for (int mi = 0; mi < 8; ++mi) {
#pragma unroll
    for (int j = 0; j < 4; ++j) {
      float pz = 0.f;
#pragma unroll
      for (int ni = 0; ni < 4; ++ni)
        pz += tanhf(acc[mi][ni][j] + hbv[ni]) * w2v[ni];
      pz += __shfl_xor(pz, 1); pz += __shfl_xor(pz, 2);
      pz += __shfl_xor(pz, 4); pz += __shfl_xor(pz, 8);
      if (r15 == 0) {
        int row = row0 + wm * 128 + mi * 16 + (qv << 2) + j;
        pe[(row << 4) + (nt << 2) + wn] = pz;   // 16 deterministic slots/row
      }
    }
  }
#undef A_LOAD0
#undef A_LOAD1
#undef A_WRITE0
#undef A_WRITE1
#undef B_ISSUE_H0
#undef B_ISSUE_H1
#undef LDA_FRAGS
#undef LDB_FRAGS
#undef PHASE_SYNC
#undef MFMA_Q
#undef TILE
}

// ---------------- kernel 4: softmax over S per batch ----------------
__global__ void softmax_kernel(const float* __restrict__ pe, float* __restrict__ alpha) {
  int b = blockIdx.x, t = threadIdx.x;
  int lane = t & 63, wid = t >> 6;
  float ev[4];
#pragma unroll
  for (int r = 0; r < 4; ++r) {
    int s = t + r * 256;
    const float* p = pe + ((b << 10) + s) * 16;
    float sum = 0.f;
#pragma unroll
    for (int i = 0; i < 16; ++i) sum += p[i];
    ev[r] = sum;
  }
  float m = fmaxf(fmaxf(ev[0], ev[1]), fmaxf(ev[2], ev[3]));
#pragma unroll
  for (int off = 32; off; off >>= 1) m = fmaxf(m, __shfl_xor(m, off));
  __shared__ float red[8];
  if (lane == 0) red[wid] = m;
  __syncthreads();
  m = fmaxf(fmaxf(red[0], red[1]), fmaxf(red[2], red[3]));
  float p4[4], ls = 0.f;
#pragma unroll
  for (int r = 0; r < 4; ++r) { p4[r] = expf(ev[r] - m); ls += p4[r]; }
#pragma unroll
  for (int off = 32; off; off >>= 1) ls += __shfl_xor(ls, off);
  if (lane == 0) red[4 + wid] = ls;
  __syncthreads();
  float inv = 1.0f / (red[4] + red[5] + red[6] + red[7]);
#pragma unroll
  for (int r = 0; r < 4; ++r) alpha[(b << 10) + t + r * 256] = p4[r] * inv;
}

// ---------------- kernel 5: context partials over s-chunks ----------------
__global__ void ctxpart_kernel(const float* __restrict__ enc, const float* __restrict__ alpha,
                               float* __restrict__ part) {
  int bid = blockIdx.x, b = bid >> 4, sc = bid & 15;
  int t = threadIdx.x;
  __shared__ float sal[64];
  if (t < 64) sal[t] = alpha[(b << 10) + (sc << 6) + t];
  __syncthreads();
  const fx4* ev = (const fx4*)enc;
  fx4 a0 = {}, a1 = {}, a2 = {};
  int base = ((b << 10) + (sc << 6)) * 768;
  for (int si = 0; si < 64; ++si) {
    float a = sal[si];
    const fx4* rp = ev + base + si * 768;
    a0 += a * rp[t];
    a1 += a * rp[256 + t];
    a2 += a * rp[512 + t];
  }
  fx4* pp = (fx4*)part;
  int pb = ((b << 4) + sc) * 768;
  pp[pb + t] = a0; pp[pb + 256 + t] = a1; pp[pb + 512 + t] = a2;
}

__global__ void ctxreduce_kernel(const float* __restrict__ part, float* __restrict__ ctx) {
  int j = blockIdx.x * 256 + threadIdx.x;     // 0..24575 fx4
  int b = j / 768, fi = j - b * 768;
  const fx4* pp = (const fx4*)part;
  fx4 s = {};
#pragma unroll
  for (int i = 0; i < 16; ++i) s += pp[((b << 4) + i) * 768 + fi];
  ((fx4*)ctx)[b * 768 + fi] = s;
}

// ---------------- kernel 6: out = ctx·W3^T + b3 ----------------
__global__ void final_kernel(const float* __restrict__ ctx, const float* __restrict__ W3,
                             const float* __restrict__ b3, float* __restrict__ out) {
  int idx = (blockIdx.x << 2) + (threadIdx.x >> 6);   // b*1024 + d
  int lane = threadIdx.x & 63;
  int b = idx >> 10, d = idx & 1023;
  const fx4* cv = (const fx4*)ctx;
  const fx4* wv = (const fx4*)W3;
  float s = 0.f;
#pragma unroll
  for (int i = 0; i < 12; ++i) {
    int f4 = lane + (i << 6);
    fx4 c = cv[b * 768 + f4];
    fx4 w = wv[d * 768 + f4];
    s += c[0] * w[0] + c[1] * w[1] + c[2] * w[2] + c[3] * w[3];
  }
#pragma unroll
  for (int off = 32; off; off >>= 1) s += __shfl_xor(s, off);
  if (lane == 0) out[idx] = s + b3[d];
}

extern "C" void kernel_launch(void* const* d_in, const int* in_sizes, int n_in,
                              void* d_out, int out_size, void* d_ws, size_t ws_size,
                              hipStream_t stream) {
  const float* hs  = (const float*)d_in[0];   // (32, 1024)
  const float* enc = (const float*)d_in[1];   // (32, 1024, 3072)
  const float* W1  = (const float*)d_in[2];   // (1024, 4096)
  const float* b1  = (const float*)d_in[3];   // (1024)
  const float* w2  = (const float*)d_in[4];   // (1, 1024)
  const float* W3  = (const float*)d_in[5];   // (1024, 3072)
  const float* b3  = (const float*)d_in[6];   // (1024)
  float* out = (float*)d_out;

  char* ws = (char*)d_ws;                     // ~15.3 MB used, write-before-read
  unsigned short* W1a = (unsigned short*)(ws);          // 6,291,456 B
  float* pe    = (float*)(ws + 6291456);                // 2,097,152 B
  float* alpha = (float*)(ws + 8388608);                // 131,072 B
  float* hb    = (float*)(ws + 8519680);                // 131,072 B
  float* ctx   = (float*)(ws + 8650752);                // 393,216 B
  float* part  = (float*)(ws + 9043968);                // 6,291,456 B

  convw1_kernel<<<3072, 256, 0, stream>>>(W1, W1a);
  hbias_kernel<<<8192, 256, 0, stream>>>(hs, W1, b1, hb);
  gemm_score<<<512, 512, 0, stream>>>(enc, W1a, hb, w2, pe);
  softmax_kernel<<<32, 256, 0, stream>>>(pe, alpha);
  ctxpart_kernel<<<512, 256, 0, stream>>>(enc, alpha, part);
  ctxreduce_kernel<<<96, 256, 0, stream>>>(part, ctx);
  final_kernel<<<8192, 256, 0, stream>>>(ctx, W3, b3, out);
}

// Round 7
// 500.440 us; speedup vs baseline: 1.1996x; 1.0806x over previous
//
#include <hip/hip_runtime.h>
#include <hip/hip_bf16.h>

// Attention_aux: fused aux-attention scorer + context + output projection.
//   1. convw1:   W1[:, :3072] -> bf16 (ws)
//   2. hbias:    hb[b,d] = hs[b,:]·W1[d,3072:] + b1[d]  (fp32)
//   3. gemm_score: bf16 MFMA  pre = enc·W1a^T ; epilogue p = sum tanh(pre+hb)*w2
//      m97-regime: 128x128 tile, BK=32, 4 waves (2x2, wave 64x64, acc 4x4),
//      dbuf 32KB LDS, counted vmcnt (never 0 mid-loop), 2 barriers/iter,
//      3 blocks/CU (the cross-block overlap that carried m97 to 874 TF).
//      A = fp32 reg-staged via cvt_pk; B via global_load_lds (pre-swizzled
//      source, rule 21). 4-slot XOR swizzle (4-way conflicts hidden).
//   4. softmax over S -> alpha
//   5. ctxpart/ctxreduce: context = alpha^T · enc  (fp32, deterministic)
//   6. final:    out = context·W3^T + b3

typedef float          fx4 __attribute__((ext_vector_type(4)));
typedef short          sv8 __attribute__((ext_vector_type(8)));
typedef unsigned short uv4 __attribute__((ext_vector_type(4)));
typedef unsigned int   ui4 __attribute__((ext_vector_type(4)));

__device__ __forceinline__ unsigned short f2bf(float x) {
  unsigned u = __float_as_uint(x);
  return (unsigned short)((u + 0x7FFFu + ((u >> 16) & 1u)) >> 16);
}

// packed RNE f32x2 -> bf16x2 via HW instruction
__device__ __forceinline__ unsigned cvtpk(float lo, float hi) {
  unsigned r;
  asm("v_cvt_pk_bf16_f32 %0, %1, %2" : "=v"(r) : "v"(lo), "v"(hi));
  return r;
}
__device__ __forceinline__ ui4 pack8(fx4 a, fx4 b) {
  ui4 v;
  v[0] = cvtpk(a[0], a[1]); v[1] = cvtpk(a[2], a[3]);
  v[2] = cvtpk(b[0], b[1]); v[3] = cvtpk(b[2], b[3]);
  return v;
}

// ---------------- kernel 1: convert W1[:, :3072] to bf16 ----------------
__global__ void convw1_kernel(const float* __restrict__ W1, unsigned short* __restrict__ W1a) {
  int id = blockIdx.x * 256 + threadIdx.x;      // float4 id, 1024*768 total
  int d = id / 768, fi = id - d * 768;
  fx4 v = ((const fx4*)W1)[d * 1024 + fi];
  uv4 r; r[0] = f2bf(v[0]); r[1] = f2bf(v[1]); r[2] = f2bf(v[2]); r[3] = f2bf(v[3]);
  ((uv4*)W1a)[d * 768 + fi] = r;
}

// ---------------- kernel 2: hidden-state bias  hb[b,d] ----------------
__global__ void hbias_kernel(const float* __restrict__ hs, const float* __restrict__ W1,
                             const float* __restrict__ b1, float* __restrict__ hb) {
  int idx = (blockIdx.x << 2) + (threadIdx.x >> 6);   // 0..32767 = b*1024+d
  int lane = threadIdx.x & 63;
  int b = idx >> 10, d = idx & 1023;
  const fx4* hv = (const fx4*)hs;
  const fx4* wv = (const fx4*)W1;
  float s = 0.f;
#pragma unroll
  for (int i = 0; i < 4; ++i) {
    int k4 = lane + (i << 6);
    fx4 h = hv[(b << 8) + k4];
    fx4 w = wv[d * 1024 + 768 + k4];
    s += h[0] * w[0] + h[1] * w[1] + h[2] * w[2] + h[3] * w[3];
  }
#pragma unroll
  for (int off = 32; off; off >>= 1) s += __shfl_xor(s, off);
  if (lane == 0) hb[idx] = s + b1[d];
}

// ---------------- kernel 3: big GEMM + tanh·w2 epilogue ----------------
// M=32768, N=1024, K=3072. Block 128x128, BK=32, 96 K-iters, 4 waves
// (2x2), wave tile 64x64 (acc 4x4 = 64 AGPR). Double-buffered LDS,
// counted vmcnt, 2 raw barriers/iter. Per-thread steady VMEM queue:
// entry [A(kt+1):4, B(kt+1):2]; A_WRITE drains A; after B_ISSUE(kt+2):
// [B(kt+1):2, A(kt+2):4, B(kt+2):2] -> vmcnt(6) retires B(kt+1).
__global__ __launch_bounds__(256, 3)
void gemm_score(const float* __restrict__ enc,
                const unsigned short* __restrict__ W1a,
                const float* __restrict__ hb,
                const float* __restrict__ w2,
                float* __restrict__ pe) {
  __shared__ __align__(16) unsigned short As[2][4096];   // [128 rows][32 k]
  __shared__ __align__(16) unsigned short Bs[2][4096];   // [128 cols][32 k]

  const int t = threadIdx.x;
  const int lane = t & 63, wid = t >> 6;
  const int wm = wid >> 1, wn = wid & 1;          // 2 x 2 wave grid

  // XCD-bijective swizzle: 2048 blocks (%8==0), XCD x owns lg [x*256,+256)
  const int bid = blockIdx.x;
  const int lg = ((bid & 7) << 8) | (bid >> 3);
  const int mt = lg >> 3, ntile = lg & 7;
  const int row0 = mt << 7;            // 128-row M tile
  const int col0 = ntile << 7;         // 128-col N tile

  const fx4* encv = (const fx4*)enc;   // enc row = 768 fx4

  // ---- A staging: thread t -> row t>>1, k-half (t&1)*16 floats = 4 fx4 ----
  const int ar = t >> 1, ah = t & 1;
  const int agb = (row0 + ar) * 768 + ah * 4;     // fx4 index; + kt*8
  const int awb = ar * 32;                        // LDS elem base of row
  const int ws0 = (((ah << 1) + 0) ^ (ar & 3)) << 3;  // swizzled 8-elem slots
  const int ws1 = (((ah << 1) + 1) ^ (ar & 3)) << 3;

  // ---- B staging: 2 gload_lds/thread; j selects 64-col half ----
  // lane l -> col_local = j*64 + wid*16 + (l>>2), dest slot l&3 (linear:
  // dest byte base(j,wid) + lane*16), source chunk pre-swizzled (rule 21)
  const int bcl = (wid << 4) + (lane >> 2);       // col within 64-half
  const int bsw = (((lane & 3) ^ ((lane >> 2) & 3)) << 3);
  const unsigned short* bsrc0 = W1a + (col0 + bcl) * 3072 + bsw;
  const unsigned short* bsrc1 = W1a + (col0 + 64 + bcl) * 3072 + bsw;
  const int bdst0 = bcl << 5;                     // elem offset (col*32)
  const int bdst1 = (64 + bcl) << 5;

  // ---- fragment read offsets (slot = q ^ (row&3)) ----
  const int r15 = lane & 15, qv = lane >> 4;
  const int offA = (wm * 64 + r15) * 32 + ((qv ^ (r15 & 3)) << 3);  // + mi*512
  const int offB = (wn * 64 + r15) * 32 + ((qv ^ (r15 & 3)) << 3);  // + ni*512

  fx4 acc[4][4] = {};
  fx4 pa[4];

#define A_LOAD(kt) { _Pragma("unroll") for (int j = 0; j < 4; ++j) pa[j] = encv[agb + (kt) * 8 + j]; }
#define A_WRITE(bq) { *(ui4*)&As[bq][awb + ws0] = pack8(pa[0], pa[1]); \
                      *(ui4*)&As[bq][awb + ws1] = pack8(pa[2], pa[3]); }
#define B_ISSUE(bq, kt)                                               \
  { __builtin_amdgcn_global_load_lds(                                 \
        (const __attribute__((address_space(1))) void*)(bsrc0 + (kt) * 32), \
        (__attribute__((address_space(3))) void*)&Bs[bq][bdst0], 16, 0, 0); \
    __builtin_amdgcn_global_load_lds(                                 \
        (const __attribute__((address_space(1))) void*)(bsrc1 + (kt) * 32), \
        (__attribute__((address_space(3))) void*)&Bs[bq][bdst1], 16, 0, 0); }
#define COMPUTE(p)                                                    \
  { sv8 af[4], bfv[4];                                                \
    _Pragma("unroll")                                                 \
    for (int mi = 0; mi < 4; ++mi) af[mi] = *(const sv8*)&As[p][offA + mi * 512]; \
    _Pragma("unroll")                                                 \
    for (int ni = 0; ni < 4; ++ni) bfv[ni] = *(const sv8*)&Bs[p][offB + ni * 512]; \
    _Pragma("unroll")                                                 \
    for (int mi = 0; mi < 4; ++mi)                                    \
      _Pragma("unroll")                                               \
      for (int ni = 0; ni < 4; ++ni)                                  \
        acc[mi][ni] = __builtin_amdgcn_mfma_f32_16x16x32_bf16(af[mi], bfv[ni], acc[mi][ni], 0, 0, 0); }
#define ITER(kt, p)                                                   \
  { COMPUTE(p)                                                        \
    if ((kt) < 95) { A_WRITE(p ^ 1) }      /* tile kt+1 -> buf p^1 */ \
    if ((kt) < 94) { A_LOAD((kt) + 2) }                               \
    __builtin_amdgcn_s_barrier();          /* readers done, buf p */  \
    if ((kt) < 94) {                                                  \
      B_ISSUE(p, (kt) + 2)                                            \
      asm volatile("s_waitcnt vmcnt(6)" ::: "memory");                \
    } else if ((kt) == 94) {                                          \
      asm volatile("s_waitcnt vmcnt(0)" ::: "memory");                \
    }                                                                 \
    asm volatile("s_waitcnt lgkmcnt(0)" ::: "memory");                \
    __builtin_amdgcn_s_barrier(); }        /* tile kt+1 published */

  // ---- prologue: fill buf0/buf1, establish in-flight invariant ----
  A_LOAD(0)
  B_ISSUE(0, 0)
  A_WRITE(0)                 // waits A(0) regs (B(0) stays in flight)
  A_LOAD(1)
  B_ISSUE(1, 1)
  asm volatile("s_waitcnt vmcnt(6)" ::: "memory");   // B(0) landed
  asm volatile("s_waitcnt lgkmcnt(0)" ::: "memory");
  __builtin_amdgcn_s_barrier();

  // ---- main loop: 96 K-tiles ----
  for (int kt2 = 0; kt2 < 48; ++kt2) {
    const int kt = kt2 * 2;
    ITER(kt, 0)
    ITER(kt + 1, 1)
  }

  // ---- epilogue: p[row] += sum_{cols in tile} tanh(acc + hb) * w2 ----
  // C layout: col = lane&15 (N), row = (lane>>4)*4 + j (M)
  const int b = row0 >> 10;
  float w2v[4], hbv[4];
#pragma unroll
  for (int ni = 0; ni < 4; ++ni) {
    int c = col0 + wn * 64 + ni * 16 + r15;
    w2v[ni] = w2[c];
    hbv[ni] = hb[(b << 10) + c];
  }
#pragma unroll
  for (int mi = 0; mi < 4; ++mi) {
#pragma unroll
    for (int j = 0; j < 4; ++j) {
      float pz = 0.f;
#pragma unroll
      for (int ni = 0; ni < 4; ++ni)
        pz += tanhf(acc[mi][ni][j] + hbv[ni]) * w2v[ni];
      pz += __shfl_xor(pz, 1); pz += __shfl_xor(pz, 2);
      pz += __shfl_xor(pz, 4); pz += __shfl_xor(pz, 8);
      if (r15 == 0) {
        int row = row0 + wm * 64 + mi * 16 + (qv << 2) + j;
        pe[(row << 4) + (ntile << 1) + wn] = pz;   // 16 slots/row
      }
    }
  }
#undef A_LOAD
#undef A_WRITE
#undef B_ISSUE
#undef COMPUTE
#undef ITER
}

// ---------------- kernel 4: softmax over S per batch ----------------
__global__ void softmax_kernel(const float* __restrict__ pe, float* __restrict__ alpha) {
  int b = blockIdx.x, t = threadIdx.x;
  int lane = t & 63, wid = t >> 6;
  float ev[4];
#pragma unroll
  for (int r = 0; r < 4; ++r) {
    int s = t + r * 256;
    const float* p = pe + ((b << 10) + s) * 16;
    float sum = 0.f;
#pragma unroll
    for (int i = 0; i < 16; ++i) sum += p[i];
    ev[r] = sum;
  }
  float m = fmaxf(fmaxf(ev[0], ev[1]), fmaxf(ev[2], ev[3]));
#pragma unroll
  for (int off = 32; off; off >>= 1) m = fmaxf(m, __shfl_xor(m, off));
  __shared__ float red[8];
  if (lane == 0) red[wid] = m;
  __syncthreads();
  m = fmaxf(fmaxf(red[0], red[1]), fmaxf(red[2], red[3]));
  float p4[4], ls = 0.f;
#pragma unroll
  for (int r = 0; r < 4; ++r) { p4[r] = expf(ev[r] - m); ls += p4[r]; }
#pragma unroll
  for (int off = 32; off; off >>= 1) ls += __shfl_xor(ls, off);
  if (lane == 0) red[4 + wid] = ls;
  __syncthreads();
  float inv = 1.0f / (red[4] + red[5] + red[6] + red[7]);
#pragma unroll
  for (int r = 0; r < 4; ++r) alpha[(b << 10) + t + r * 256] = p4[r] * inv;
}

// ---------------- kernel 5: context partials over s-chunks ----------------
__global__ void ctxpart_kernel(const float* __restrict__ enc, const float* __restrict__ alpha,
                               float* __restrict__ part) {
  int bid = blockIdx.x, b = bid >> 4, sc = bid & 15;
  int t = threadIdx.x;
  __shared__ float sal[64];
  if (t < 64) sal[t] = alpha[(b << 10) + (sc << 6) + t];
  __syncthreads();
  const fx4* ev = (const fx4*)enc;
  fx4 a0 = {}, a1 = {}, a2 = {};
  int base = ((b << 10) + (sc << 6)) * 768;
  for (int si = 0; si < 64; ++si) {
    float a = sal[si];
    const fx4* rp = ev + base + si * 768;
    a0 += a * rp[t];
    a1 += a * rp[256 + t];
    a2 += a * rp[512 + t];
  }
  fx4* pp = (fx4*)part;
  int pb = ((b << 4) + sc) * 768;
  pp[pb + t] = a0; pp[pb + 256 + t] = a1; pp[pb + 512 + t] = a2;
}

__global__ void ctxreduce_kernel(const float* __restrict__ part, float* __restrict__ ctx) {
  int j = blockIdx.x * 256 + threadIdx.x;     // 0..24575 fx4
  int b = j / 768, fi = j - b * 768;
  const fx4* pp = (const fx4*)part;
  fx4 s = {};
#pragma unroll
  for (int i = 0; i < 16; ++i) s += pp[((b << 4) + i) * 768 + fi];
  ((fx4*)ctx)[b * 768 + fi] = s;
}

// ---------------- kernel 6: out = ctx·W3^T + b3 ----------------
__global__ void final_kernel(const float* __restrict__ ctx, const float* __restrict__ W3,
                             const float* __restrict__ b3, float* __restrict__ out) {
  int idx = (blockIdx.x << 2) + (threadIdx.x >> 6);   // b*1024 + d
  int lane = threadIdx.x & 63;
  int b = idx >> 10, d = idx & 1023;
  const fx4* cv = (const fx4*)ctx;
  const fx4* wv = (const fx4*)W3;
  float s = 0.f;
#pragma unroll
  for (int i = 0; i < 12; ++i) {
    int f4 = lane + (i << 6);
    fx4 c = cv[b * 768 + f4];
    fx4 w = wv[d * 768 + f4];
    s += c[0] * w[0] + c[1] * w[1] + c[2] * w[2] + c[3] * w[3];
  }
#pragma unroll
  for (int off = 32; off; off >>= 1) s += __shfl_xor(s, off);
  if (lane == 0) out[idx] = s + b3[d];
}

extern "C" void kernel_launch(void* const* d_in, const int* in_sizes, int n_in,
                              void* d_out, int out_size, void* d_ws, size_t ws_size,
                              hipStream_t stream) {
  const float* hs  = (const float*)d_in[0];   // (32, 1024)
  const float* enc = (const float*)d_in[1];   // (32, 1024, 3072)
  const float* W1  = (const float*)d_in[2];   // (1024, 4096)
  const float* b1  = (const float*)d_in[3];   // (1024)
  const float* w2  = (const float*)d_in[4];   // (1, 1024)
  const float* W3  = (const float*)d_in[5];   // (1024, 3072)
  const float* b3  = (const float*)d_in[6];   // (1024)
  float* out = (float*)d_out;

  char* ws = (char*)d_ws;                     // ~15.3 MB used, write-before-read
  unsigned short* W1a = (unsigned short*)(ws);          // 6,291,456 B
  float* pe    = (float*)(ws + 6291456);                // 2,097,152 B
  float* alpha = (float*)(ws + 8388608);                // 131,072 B
  float* hb    = (float*)(ws + 8519680);                // 131,072 B
  float* ctx   = (float*)(ws + 8650752);                // 393,216 B
  float* part  = (float*)(ws + 9043968);                // 6,291,456 B

  convw1_kernel<<<3072, 256, 0, stream>>>(W1, W1a);
  hbias_kernel<<<8192, 256, 0, stream>>>(hs, W1, b1, hb);
  gemm_score<<<2048, 256, 0, stream>>>(enc, W1a, hb, w2, pe);
  softmax_kernel<<<32, 256, 0, stream>>>(pe, alpha);
  ctxpart_kernel<<<512, 256, 0, stream>>>(enc, alpha, part);
  ctxreduce_kernel<<<96, 256, 0, stream>>>(part, ctx);
  final_kernel<<<8192, 256, 0, stream>>>(ctx, W3, b3, out);
}